// Round 4
// baseline (213.547 us; speedup 1.0000x reference)
//
#include <hip/hip_runtime.h>
#include <math.h>

#define HH 160
#define WW 160
#define HWSZ 25600
#define TR 22
#define TC 22
#define NSLOT 484   // TR*TC tile slots, margin +-3 around 16x16 px tile

typedef __attribute__((ext_vector_type(8))) short short8;
typedef __attribute__((ext_vector_type(4))) short short4v;
typedef __attribute__((ext_vector_type(8))) _Float16 half8;
typedef __attribute__((ext_vector_type(2))) _Float16 half2v;
typedef __attribute__((ext_vector_type(4))) float f32x4;

__device__ __forceinline__ short f2h(float f) {
  union { _Float16 h; short s; } u; u.h = (_Float16)f; return u.s;
}
__device__ __forceinline__ float h2f(short s) {
  union { _Float16 h; short s; } u; u.s = s; return (float)u.h;
}
__device__ __forceinline__ half2v bcast_h(short s) {
  unsigned int x = (unsigned short)s; x |= x << 16;
  union { unsigned int u; half2v h; } v; v.u = x; return v.h;
}

// ---------------------------------------------------------------------------
// pre: blocks [0,1600): transpose x f32 NCHW -> f16 NHWC.
//      blocks [1600,1664): BN fold + weight reorder to A-frag layout.
// dcn w: [f18][ot4][q4][m16][j8] = w[ot*16+m][c*9+k], kp=f*32+q*8+j
//        (lane l=q*16+m reads LDS byte l*16 -> contiguous 1KB wave access)
// om  w: [f18][ot2][m16][q4][j8], oc>=27 zero-padded (read from global)
__global__ __launch_bounds__(256) void pre_kernel(
    const float* __restrict__ x,
    const float* __restrict__ g1, const float* __restrict__ b1,
    const float* __restrict__ m1, const float* __restrict__ v1,
    const float* __restrict__ g2, const float* __restrict__ b2,
    const float* __restrict__ m2, const float* __restrict__ v2,
    const float* __restrict__ wd1, const float* __restrict__ wd2,
    const float* __restrict__ wo1, const float* __restrict__ wo2,
    float* __restrict__ sc, short* __restrict__ wd1h, short* __restrict__ wd2h,
    short* __restrict__ wo1h, short* __restrict__ wo2h,
    short* __restrict__ xcl) {
  __shared__ short tmp[64][72];
  int t = threadIdx.x;
  int bx = blockIdx.x;
  if (bx < 1600) {
    int b = bx / 400, p0 = (bx - b * 400) * 64;
    const float* xb = x + (size_t)b * 64 * HWSZ;
    for (int i = t; i < 4096; i += 256) {
      int c = i >> 6, p = i & 63;
      tmp[p][c] = f2h(xb[c * HWSZ + p0 + p]);
    }
    __syncthreads();
    short* ob = xcl + ((size_t)b * HWSZ + p0) * 64;
    for (int i = t; i < 512; i += 256) {
      int p = i >> 3, g = i & 7;
      *(short8*)&ob[p * 64 + g * 8] = *(const short8*)&tmp[p][g * 8];
    }
    return;
  }
  int i0 = (bx - 1600) * 256 + t;  // 0..16383
  for (int i = i0; i < 36864; i += 16384) {
    int j = i & 7, m = (i >> 3) & 15, q = (i >> 7) & 3;
    int ot = (i >> 9) & 3, f = i >> 11;
    int kp = f * 32 + q * 8 + j;
    int k = kp >> 6, c = kp & 63;
    int src = (ot * 16 + m) * 576 + c * 9 + k;
    wd1h[i] = f2h(wd1[src]);
    wd2h[i] = f2h(wd2[src]);
  }
  for (int i = i0; i < 18432; i += 16384) {
    int j = i & 7, q = (i >> 3) & 3, m = (i >> 5) & 15;
    int ot = (i >> 9) & 1, f = i >> 10;
    int kp = f * 32 + q * 8 + j;
    int k = kp >> 6, c = kp & 63;
    int oc = ot * 16 + m;
    wo1h[i] = (oc < 27) ? f2h(wo1[oc * 576 + c * 9 + k]) : (short)0;
    wo2h[i] = (oc < 27) ? f2h(wo2[oc * 576 + c * 9 + k]) : (short)0;
  }
  if (i0 < 64) {
    float s1 = g1[i0] * rsqrtf(v1[i0] + 1e-5f);
    sc[i0]       = s1;
    sc[64 + i0]  = b1[i0] - m1[i0] * s1;
    float s2 = g2[i0] * rsqrtf(v2[i0] + 1e-5f);
    sc[128 + i0] = s2;
    sc[192 + i0] = b2[i0] - m2[i0] * s2;
  }
}

// ---------------------------------------------------------------------------
// dcn_fused: offset-conv (27ch) + modulated deform conv (64->64) + BN
//            + optional residual + GELU, all from one staged tile.
// Block: 16x * 16y px, 1024 thr / 16 waves. Wave w owns pixel row y0+w.
// FULL dcn weight tensor (72 KB) staged into LDS once per block -> the
// 9-tap loop has ZERO barriers, zero staging, zero global traffic: pure
// ds_read + VALU + MFMA, fully unrolled, pipelined across taps by the
// scheduler with 16 waves slipping freely. 2 barriers per block total.
// LDS = xt 61952 + wl 73728 + oms 18432 = 154112 B -> 1 block/CU, 16 waves.
__global__ __launch_bounds__(1024) void dcn_fused(
    const short* __restrict__ xcl,     // [B][HW][64] f16 NHWC
    const short* __restrict__ who,     // om weights  [f][2][16][4][8]
    const float* __restrict__ bias_om, // 27
    const short* __restrict__ whd,     // dcn weights [f][4][4][16][8]
    const float* __restrict__ scale, const float* __restrict__ shift,
    const short* __restrict__ id_cl,     // f16 NHWC residual or null
    short* __restrict__ out_cl,          // f16 NHWC (layer 1) or null
    float* __restrict__ out_f32) {       // f32 NCHW (layer 2) or null
  __shared__ short xt[NSLOT * 64];           // 61952 B, 16B groups swizzled
  __shared__ __align__(16) short wl[36864];  // full dcn weights (73728 B)
  __shared__ __align__(16) short oms[9216];  // om scratch (18432 B)

  int t = threadIdx.x;
  int x0 = blockIdx.x * 16, y0 = blockIdx.y * 16, b = blockIdx.z;
  int w = t >> 6, lane = t & 63, q = lane >> 4, m = lane & 15;
  int ybase = y0 - 3, xbase = x0 - 3;

  // ---- stage full weight tensor (one-time; 36864 halves / 1024 thr) ----
  for (int i = t; i < 4608; i += 1024)
    *(short8*)&wl[i * 8] = *(const short8*)&whd[i * 8];

  // ---- stage tile (coalesced b128 copies) ----
  const short* xb = xcl + (size_t)b * HWSZ * 64;
  for (int i = t; i < NSLOT * 8; i += 1024) {
    int slot = i >> 3, g = i & 7;
    int ty = slot / TC, tx = slot - ty * TC;
    int gy = ybase + ty, gx = xbase + tx;
    short8 v = {};
    if (gy >= 0 && gy < HH && gx >= 0 && gx < WW)
      v = *(const short8*)&xb[(gy * WW + gx) * 64 + g * 8];
    *(short8*)&xt[slot * 64 + ((g ^ (slot & 7)) << 3)] = v;
  }
  __syncthreads();  // xt + wl visible

  // ---- om GEMM: wave w -> 27 oc x 16 px of row y0+w -> oms scratch ----
  {
    f32x4 oacc0 = {}, oacc1 = {};
#pragma unroll 6
    for (int f = 0; f < 18; f++) {
      int k = f >> 1;
      int ki = k / 3, kj = k - ki * 3;
      int g = (f & 1) * 4 + q;
      int slotb = (w + ki + 2) * TC + (m + kj + 2);
      short8 bv = *(const short8*)&xt[slotb * 64 + ((g ^ (slotb & 7)) << 3)];
      const short* ap = who + (f * 128 + m * 4 + q) * 8;
      short8 a0 = *(const short8*)ap;
      short8 a1 = *(const short8*)(ap + 512);
      union { short8 s8; half8 h; } A0, A1, B;
      A0.s8 = a0; A1.s8 = a1; B.s8 = bv;
      oacc0 = __builtin_amdgcn_mfma_f32_16x16x32_f16(A0.h, B.h, oacc0, 0, 0, 0);
      oacc1 = __builtin_amdgcn_mfma_f32_16x16x32_f16(A1.h, B.h, oacc1, 0, 0, 0);
    }
    int px = w * 16 + m;
#pragma unroll
    for (int mt = 0; mt < 2; mt++) {
      f32x4 oa = mt ? oacc1 : oacc0;
      short4v pv;
#pragma unroll
      for (int r = 0; r < 4; r++) {
        int oc = mt * 16 + q * 4 + r;
        float bb = (oc < 27) ? bias_om[oc] : 0.f;
        pv[r] = f2h(oa[r] + bb);
      }
      *(short4v*)&oms[px * 36 + mt * 16 + q * 4] = pv;  // stride 36 (8B-aligned)
    }
  }
  __syncthreads();  // oms visible (never overwritten afterwards)

  // ---- pull this lane's pixel om values (36 ch) into registers ----
  union { short s[36]; short4v v4[9]; } omr;
  {
    int px = w * 16 + m;
#pragma unroll
    for (int i = 0; i < 9; i++)
      omr.v4[i] = *(const short4v*)&oms[px * 36 + i * 4];
  }

  int y = y0 + w, x = x0 + m;

  // hoist layer-2 residual load above the tap loop (hides HBM latency)
  short4v ivs[4];
  if (out_f32) {
    size_t pbase = ((size_t)b * HWSZ + y * WW + x) * 64;
#pragma unroll
    for (int ot = 0; ot < 4; ot++)
      ivs[ot] = *(const short4v*)&id_cl[pbase + ot * 16 + q * 4];
  }

  // ---- main GEMM: 64 oc x 16 px, K=576; barrier-free tap loop ----
  f32x4 acc[4] = {};
#pragma unroll
  for (int k = 0; k < 9; k++) {
    // inline meta for this lane's pixel (verbatim formulas)
    float dy = h2f(omr.s[2 * k]);
    float dx = h2f(omr.s[2 * k + 1]);
    float ml = h2f(omr.s[18 + k]);
    float msk = 1.f / (1.f + __expf(-ml));
    int ki = k / 3, kj = k - ki * 3;
    float py  = (float)(y - 1 + ki) + dy;
    float pxf = (float)(x - 1 + kj) + dx;
    float fy = floorf(py), fx = floorf(pxf);
    float ly = py - fy, lx = pxf - fx;
    int yi0 = (int)fy, xi0 = (int)fx;
    bool vy0 = (yi0 >= 0) & (yi0 < HH), vy1 = (yi0 + 1 >= 0) & (yi0 + 1 < HH);
    bool vx0 = (xi0 >= 0) & (xi0 < WW), vx1 = (xi0 + 1 >= 0) & (xi0 + 1 < WW);
    int ty0 = min(max(yi0 - ybase, 0), TR - 2);
    int tx0 = min(max(xi0 - xbase, 0), TC - 2);
    int p00 = ty0 * TC + tx0;
    half2v w00 = bcast_h(f2h((vy0 & vx0) ? (1.f - ly) * (1.f - lx) * msk : 0.f));
    half2v w01 = bcast_h(f2h((vy0 & vx1) ? (1.f - ly) * lx * msk : 0.f));
    half2v w10 = bcast_h(f2h((vy1 & vx0) ? ly * (1.f - lx) * msk : 0.f));
    half2v w11 = bcast_h(f2h((vy1 & vx1) ? ly * lx * msk : 0.f));
    int s00 = p00, s01 = p00 + 1, s10 = p00 + TC, s11 = p00 + TC + 1;
#pragma unroll
    for (int ch = 0; ch < 2; ch++) {
      int g = ch * 4 + q;
      // conflict-free A layout: lane l=q*16+m reads contiguous 16B at l*16
      const short* ap = wl + k * 4096 + ch * 2048 + (q * 16 + m) * 8;
      short8 a0 = *(const short8*)ap;
      short8 a1 = *(const short8*)(ap + 512);
      short8 a2 = *(const short8*)(ap + 1024);
      short8 a3 = *(const short8*)(ap + 1536);
      union { short8 s8; half2v h[4]; } c00, c01, c10, c11, bb;
      c00.s8 = *(const short8*)&xt[s00 * 64 + ((g ^ (s00 & 7)) << 3)];
      c01.s8 = *(const short8*)&xt[s01 * 64 + ((g ^ (s01 & 7)) << 3)];
      c10.s8 = *(const short8*)&xt[s10 * 64 + ((g ^ (s10 & 7)) << 3)];
      c11.s8 = *(const short8*)&xt[s11 * 64 + ((g ^ (s11 & 7)) << 3)];
#pragma unroll
      for (int d = 0; d < 4; d++)
        bb.h[d] = c00.h[d] * w00 + c01.h[d] * w01 + c10.h[d] * w10 +
                  c11.h[d] * w11;
      union { short8 s8; half8 h8; } B, A0, A1, A2, A3;
      B.s8 = bb.s8; A0.s8 = a0; A1.s8 = a1; A2.s8 = a2; A3.s8 = a3;
      acc[0] = __builtin_amdgcn_mfma_f32_16x16x32_f16(A0.h8, B.h8, acc[0], 0, 0, 0);
      acc[1] = __builtin_amdgcn_mfma_f32_16x16x32_f16(A1.h8, B.h8, acc[1], 0, 0, 0);
      acc[2] = __builtin_amdgcn_mfma_f32_16x16x32_f16(A2.h8, B.h8, acc[2], 0, 0, 0);
      acc[3] = __builtin_amdgcn_mfma_f32_16x16x32_f16(A3.h8, B.h8, acc[3], 0, 0, 0);
    }
  }

  // ---- epilogue ----
  // D layout: acc[ot] = oc tile ot; oc = ot*16 + q*4 + r; px col = m, row = w
  if (out_f32) {  // layer 2: BN + residual (f16 NHWC) + GELU -> f32 NCHW
#pragma unroll
    for (int ot = 0; ot < 4; ot++) {
#pragma unroll
      for (int r = 0; r < 4; r++) {
        int oc = ot * 16 + q * 4 + r;
        size_t idx = ((size_t)(b * 64 + oc)) * HWSZ + y * WW + x;
        float v = acc[ot][r] * scale[oc] + shift[oc] + h2f(ivs[ot][r]);
        v = 0.5f * v * (1.f + erff(v * 0.70710678118654752f));
        out_f32[idx] = v;
      }
    }
  } else {  // layer 1: BN + GELU -> f16 NHWC
    size_t base = ((size_t)b * HWSZ + y * WW + x) * 64;
#pragma unroll
    for (int ot = 0; ot < 4; ot++) {
      short4v pv;
#pragma unroll
      for (int r = 0; r < 4; r++) {
        int oc = ot * 16 + q * 4 + r;
        float v = acc[ot][r] * scale[oc] + shift[oc];
        v = 0.5f * v * (1.f + erff(v * 0.70710678118654752f));
        pv[r] = f2h(v);
      }
      *(short4v*)&out_cl[base + ot * 16 + q * 4] = pv;
    }
  }
}

// ---------------------------------------------------------------------------
extern "C" void kernel_launch(void* const* d_in, const int* in_sizes, int n_in,
                              void* d_out, int out_size, void* d_ws, size_t ws_size,
                              hipStream_t stream) {
  const float* x     = (const float*)d_in[0];
  const float* w_om1 = (const float*)d_in[1];
  const float* b_om1 = (const float*)d_in[2];
  const float* w_d1  = (const float*)d_in[3];
  const float* bn1g  = (const float*)d_in[4];
  const float* bn1b  = (const float*)d_in[5];
  const float* bn1m  = (const float*)d_in[6];
  const float* bn1v  = (const float*)d_in[7];
  const float* w_om2 = (const float*)d_in[8];
  const float* b_om2 = (const float*)d_in[9];
  const float* w_d2  = (const float*)d_in[10];
  const float* bn2g  = (const float*)d_in[11];
  const float* bn2b  = (const float*)d_in[12];
  const float* bn2m  = (const float*)d_in[13];
  const float* bn2v  = (const float*)d_in[14];

  float* ws    = (float*)d_ws;
  float* sc    = ws;                       // 256 f
  short* w1h   = (short*)(ws + 256);       // 36864 halves
  short* w2h   = w1h + 36864;
  short* wo1h  = w2h + 36864;              // 18432 halves
  short* wo2h  = wo1h + 18432;
  short* x_cl  = (short*)(ws + 55552);     // 6,553,600 halves
  short* o1_cl = x_cl + 6553600;           // 6,553,600 halves
  float* outp  = (float*)d_out;

  pre_kernel<<<dim3(1664), dim3(256), 0, stream>>>(
      x, bn1g, bn1b, bn1m, bn1v, bn2g, bn2b, bn2m, bn2v,
      w_d1, w_d2, w_om1, w_om2, sc, w1h, w2h, wo1h, wo2h, x_cl);

  dim3 grid(WW / 16, HH / 16, 4);
  dcn_fused<<<grid, dim3(1024), 0, stream>>>(
      x_cl, wo1h, b_om1, w1h, sc, sc + 64, nullptr, o1_cl, nullptr);
  dcn_fused<<<grid, dim3(1024), 0, stream>>>(
      o1_cl, wo2h, b_om2, w2h, sc + 128, sc + 192, x_cl, nullptr, outp);
}

// Round 5
// 208.984 us; speedup vs baseline: 1.0218x; 1.0218x over previous
//
#include <hip/hip_runtime.h>
#include <math.h>

#define HH 160
#define WW 160
#define HWSZ 25600
#define TR 14
#define TC 22
#define NSLOT 308   // TR*TC tile slots, margin +-3 around 16x8 px tile

typedef __attribute__((ext_vector_type(8))) short short8;
typedef __attribute__((ext_vector_type(4))) short short4v;
typedef __attribute__((ext_vector_type(8))) _Float16 half8;
typedef __attribute__((ext_vector_type(2))) _Float16 half2v;
typedef __attribute__((ext_vector_type(4))) float f32x4;
typedef __attribute__((ext_vector_type(16))) float f32x16;

__device__ __forceinline__ short f2h(float f) {
  union { _Float16 h; short s; } u; u.h = (_Float16)f; return u.s;
}
__device__ __forceinline__ float h2f(short s) {
  union { _Float16 h; short s; } u; u.s = s; return (float)u.h;
}
__device__ __forceinline__ half2v bcast_h(short s) {
  unsigned int x = (unsigned short)s; x |= x << 16;
  union { unsigned int u; half2v h; } v; v.u = x; return v.h;
}

// ---------------------------------------------------------------------------
// pre: blocks [0,1600): transpose x f32 NCHW -> f16 NHWC.
//      blocks [1600,1664): BN fold + weight reorder to A-frag layouts.
// dcn w (32x32x16 A-frag): [tap9][s4][ot2][hi2][oc32][j8]
//      element (oc_g=ot*32+oc, c=s*16+hi*8+j, tap); lane l reads l*16B
//      contiguous per (s,ot) -> conflict-free 1KB wave access.
// om  w (16x16x32 A-frag): [f18][ot2][m16][q4][j8], oc>=27 zero-padded
__global__ __launch_bounds__(256) void pre_kernel(
    const float* __restrict__ x,
    const float* __restrict__ g1, const float* __restrict__ b1,
    const float* __restrict__ m1, const float* __restrict__ v1,
    const float* __restrict__ g2, const float* __restrict__ b2,
    const float* __restrict__ m2, const float* __restrict__ v2,
    const float* __restrict__ wd1, const float* __restrict__ wd2,
    const float* __restrict__ wo1, const float* __restrict__ wo2,
    float* __restrict__ sc, short* __restrict__ wd1h, short* __restrict__ wd2h,
    short* __restrict__ wo1h, short* __restrict__ wo2h,
    short* __restrict__ xcl) {
  __shared__ short tmp[64][72];
  int t = threadIdx.x;
  int bx = blockIdx.x;
  if (bx < 1600) {
    int b = bx / 400, p0 = (bx - b * 400) * 64;
    const float* xb = x + (size_t)b * 64 * HWSZ;
    for (int i = t; i < 4096; i += 256) {
      int c = i >> 6, p = i & 63;
      tmp[p][c] = f2h(xb[c * HWSZ + p0 + p]);
    }
    __syncthreads();
    short* ob = xcl + ((size_t)b * HWSZ + p0) * 64;
    for (int i = t; i < 512; i += 256) {
      int p = i >> 3, g = i & 7;
      *(short8*)&ob[p * 64 + g * 8] = *(const short8*)&tmp[p][g * 8];
    }
    return;
  }
  int i0 = (bx - 1600) * 256 + t;  // 0..16383
  for (int i = i0; i < 36864; i += 16384) {
    int j = i & 7, oc = (i >> 3) & 31, hi = (i >> 8) & 1;
    int ot = (i >> 9) & 1, s = (i >> 10) & 3, tap = i >> 12;
    int src = (ot * 32 + oc) * 576 + (s * 16 + hi * 8 + j) * 9 + tap;
    wd1h[i] = f2h(wd1[src]);
    wd2h[i] = f2h(wd2[src]);
  }
  for (int i = i0; i < 18432; i += 16384) {
    int j = i & 7, q = (i >> 3) & 3, m = (i >> 5) & 15;
    int ot = (i >> 9) & 1, f = i >> 10;
    int kp = f * 32 + q * 8 + j;
    int k = kp >> 6, c = kp & 63;
    int oc = ot * 16 + m;
    wo1h[i] = (oc < 27) ? f2h(wo1[oc * 576 + c * 9 + k]) : (short)0;
    wo2h[i] = (oc < 27) ? f2h(wo2[oc * 576 + c * 9 + k]) : (short)0;
  }
  if (i0 < 64) {
    float s1 = g1[i0] * rsqrtf(v1[i0] + 1e-5f);
    sc[i0]       = s1;
    sc[64 + i0]  = b1[i0] - m1[i0] * s1;
    float s2 = g2[i0] * rsqrtf(v2[i0] + 1e-5f);
    sc[128 + i0] = s2;
    sc[192 + i0] = b2[i0] - m2[i0] * s2;
  }
}

// ---------------------------------------------------------------------------
// dcn_fused: offset-conv (27ch) + modulated deform conv (64->64) + BN
//            + optional residual + GELU, all from one staged tile.
// Block: 16x * 8y px, 256 thr / 4 waves. Main GEMM uses 32x32x16 MFMA:
// wave w owns 32 px (rows y0+2w, y0+2w+1); B-frag px=lane&31, hi=lane>>5
// -> only 2 lanes/px compute sampling meta (was 4 with 16x16), and the
// 8KB A panel serves 32 px (256 B/px, was 512). Weights staged in 3-tap
// groups (24 KB) -> 3 barrier-free taps between stages, 8 barriers/block.
// LDS = xt 39424 + wA 24576 + oms 9216 = 73216 B -> 2 blocks/CU = 8 waves,
// so one block's barrier drains overlap the other's compute.
__global__ __launch_bounds__(256, 2) void dcn_fused(
    const short* __restrict__ xcl,     // [B][HW][64] f16 NHWC
    const short* __restrict__ who,     // om weights  [f][2][16][4][8]
    const float* __restrict__ bias_om, // 27
    const short* __restrict__ whd,     // dcn weights [tap][s][ot][hi][oc][j]
    const float* __restrict__ scale, const float* __restrict__ shift,
    const short* __restrict__ id_cl,     // f16 NHWC residual or null
    short* __restrict__ out_cl,          // f16 NHWC (layer 1) or null
    float* __restrict__ out_f32) {       // f32 NCHW (layer 2) or null
  __shared__ short xt[NSLOT * 64];           // 39424 B, 16B groups swizzled
  __shared__ __align__(16) short wA[12288];  // 3-tap weight group (24576 B)
  __shared__ __align__(16) short oms[4608];  // om scratch (9216 B)

  int t = threadIdx.x;
  int x0 = blockIdx.x * 16, y0 = blockIdx.y * 8, b = blockIdx.z;
  int w = t >> 6, lane = t & 63, q = lane >> 4, m = lane & 15;
  int hi = lane >> 5, p31 = lane & 31;
  int ybase = y0 - 3, xbase = x0 - 3;

  // early-issue global loads of tap-group 0 (24576 B / 256 thr = 96 B/thr)
  short8 pr[6];
#pragma unroll
  for (int c = 0; c < 6; c++)
    pr[c] = *(const short8*)&whd[c * 2048 + t * 8];

  // ---- stage tile (coalesced b128 copies) ----
  const short* xb = xcl + (size_t)b * HWSZ * 64;
  for (int i = t; i < NSLOT * 8; i += 256) {
    int slot = i >> 3, g = i & 7;
    int ty = slot / TC, tx = slot - ty * TC;
    int gy = ybase + ty, gx = xbase + tx;
    short8 v = {};
    if (gy >= 0 && gy < HH && gx >= 0 && gx < WW)
      v = *(const short8*)&xb[(gy * WW + gx) * 64 + g * 8];
    *(short8*)&xt[slot * 64 + ((g ^ (slot & 7)) << 3)] = v;
  }
  // write tap-group 0 into wA, then issue group-1 loads
#pragma unroll
  for (int c = 0; c < 6; c++)
    *(short8*)&wA[c * 2048 + t * 8] = pr[c];
#pragma unroll
  for (int c = 0; c < 6; c++)
    pr[c] = *(const short8*)&whd[12288 + c * 2048 + t * 8];
  __syncthreads();  // xt + wA(g0) visible

  // ---- om GEMM (16x16x32): wave w -> 27 oc x 32 px (2 px-tiles) ----
  {
    f32x4 oacc[2][2] = {};
#pragma unroll 6
    for (int f = 0; f < 18; f++) {
      int k = f >> 1;
      int ki = k / 3, kj = k - ki * 3;
      int g = (f & 1) * 4 + q;
      const short* ap = who + (f * 128 + m * 4 + q) * 8;
      short8 a0 = *(const short8*)ap;
      short8 a1 = *(const short8*)(ap + 512);
      union { short8 s8; half8 h; } A0, A1;
      A0.s8 = a0; A1.s8 = a1;
#pragma unroll
      for (int p = 0; p < 2; p++) {
        int slotb = (w * 2 + p + ki + 2) * TC + (m + kj + 2);
        union { short8 s8; half8 h; } B;
        B.s8 = *(const short8*)&xt[slotb * 64 + ((g ^ (slotb & 7)) << 3)];
        oacc[p][0] = __builtin_amdgcn_mfma_f32_16x16x32_f16(A0.h, B.h, oacc[p][0], 0, 0, 0);
        oacc[p][1] = __builtin_amdgcn_mfma_f32_16x16x32_f16(A1.h, B.h, oacc[p][1], 0, 0, 0);
      }
    }
#pragma unroll
    for (int p = 0; p < 2; p++) {
      int px = w * 32 + p * 16 + m;
#pragma unroll
      for (int mt = 0; mt < 2; mt++) {
        short4v pv;
#pragma unroll
        for (int r = 0; r < 4; r++) {
          int oc = mt * 16 + q * 4 + r;
          float bb = (oc < 27) ? bias_om[oc] : 0.f;
          pv[r] = f2h(oacc[p][mt][r] + bb);
        }
        *(short4v*)&oms[px * 36 + mt * 16 + q * 4] = pv;  // stride 36
      }
    }
  }
  __syncthreads();  // oms visible (never overwritten afterwards)

  // ---- pull this lane's pixel om values (36 ch) into registers ----
  union { short s[36]; short4v v4[9]; } omr;
  {
    int px = w * 32 + p31;
#pragma unroll
    for (int i = 0; i < 9; i++)
      omr.v4[i] = *(const short4v*)&oms[px * 36 + i * 4];
  }

  int y = y0 + w * 2 + (p31 >> 4), x = x0 + m;

  // hoist layer-2 residual load above the tap loop (hides HBM latency)
  short4v ivs[8];
  if (out_f32) {
    size_t pbase = ((size_t)b * HWSZ + y * WW + x) * 64;
#pragma unroll
    for (int ot = 0; ot < 2; ot++)
#pragma unroll
      for (int blk = 0; blk < 4; blk++)
        ivs[ot * 4 + blk] =
            *(const short4v*)&id_cl[pbase + ot * 32 + blk * 8 + hi * 4];
  }

  // ---- main GEMM (32x32x16): 64 oc x 32 px/wave, K=576 ----
  f32x16 acc0 = {}, acc1 = {};
#pragma unroll
  for (int grp = 0; grp < 3; ++grp) {
    if (grp > 0) {
      __syncthreads();  // all waves done reading previous group
#pragma unroll
      for (int c = 0; c < 6; c++)
        *(short8*)&wA[c * 2048 + t * 8] = pr[c];
      if (grp < 2) {
#pragma unroll
        for (int c = 0; c < 6; c++)
          pr[c] = *(const short8*)&whd[(grp + 1) * 12288 + c * 2048 + t * 8];
      }
      __syncthreads();  // wA(grp) visible
    }
#pragma unroll
    for (int kt = 0; kt < 3; ++kt) {
      const int k = grp * 3 + kt;
      // inline meta for this lane's pixel (verbatim formulas)
      float dy = h2f(omr.s[2 * k]);
      float dx = h2f(omr.s[2 * k + 1]);
      float ml = h2f(omr.s[18 + k]);
      float msk = 1.f / (1.f + __expf(-ml));
      int ki = k / 3, kj = k - ki * 3;
      float py  = (float)(y - 1 + ki) + dy;
      float pxf = (float)(x - 1 + kj) + dx;
      float fy = floorf(py), fx = floorf(pxf);
      float ly = py - fy, lx = pxf - fx;
      int yi0 = (int)fy, xi0 = (int)fx;
      bool vy0 = (yi0 >= 0) & (yi0 < HH), vy1 = (yi0 + 1 >= 0) & (yi0 + 1 < HH);
      bool vx0 = (xi0 >= 0) & (xi0 < WW), vx1 = (xi0 + 1 >= 0) & (xi0 + 1 < WW);
      int ty0 = min(max(yi0 - ybase, 0), TR - 2);
      int tx0 = min(max(xi0 - xbase, 0), TC - 2);
      int p00 = ty0 * TC + tx0;
      half2v w00 = bcast_h(f2h((vy0 & vx0) ? (1.f - ly) * (1.f - lx) * msk : 0.f));
      half2v w01 = bcast_h(f2h((vy0 & vx1) ? (1.f - ly) * lx * msk : 0.f));
      half2v w10 = bcast_h(f2h((vy1 & vx0) ? ly * (1.f - lx) * msk : 0.f));
      half2v w11 = bcast_h(f2h((vy1 & vx1) ? ly * lx * msk : 0.f));
      int s00 = p00, s01 = p00 + 1, s10 = p00 + TC, s11 = p00 + TC + 1;
#pragma unroll
      for (int s = 0; s < 4; s++) {
        int g = s * 2 + hi;  // 16B ch-group this lane consumes for slice s
        union { short8 s8; half2v h[4]; } c00, c01, c10, c11, bb;
        c00.s8 = *(const short8*)&xt[s00 * 64 + ((g ^ (s00 & 7)) << 3)];
        c01.s8 = *(const short8*)&xt[s01 * 64 + ((g ^ (s01 & 7)) << 3)];
        c10.s8 = *(const short8*)&xt[s10 * 64 + ((g ^ (s10 & 7)) << 3)];
        c11.s8 = *(const short8*)&xt[s11 * 64 + ((g ^ (s11 & 7)) << 3)];
#pragma unroll
        for (int d = 0; d < 4; d++)
          bb.h[d] = c00.h[d] * w00 + c01.h[d] * w01 + c10.h[d] * w10 +
                    c11.h[d] * w11;
        // A-frags: lane l reads contiguous 16B at (s,ot) 1KB panels
        const short* ap = wA + kt * 4096 + s * 1024 + lane * 8;
        short8 a0 = *(const short8*)ap;
        short8 a1 = *(const short8*)(ap + 512);
        union { short8 s8; half8 h8; } B, A0, A1;
        B.s8 = bb.s8; A0.s8 = a0; A1.s8 = a1;
        acc0 = __builtin_amdgcn_mfma_f32_32x32x16_f16(A0.h8, B.h8, acc0, 0, 0, 0);
        acc1 = __builtin_amdgcn_mfma_f32_32x32x16_f16(A1.h8, B.h8, acc1, 0, 0, 0);
      }
    }
  }

  // ---- epilogue ----
  // D layout (32x32): col px = lane&31; row oc_in_tile = (r&3)+8*(r>>2)+4*hi
  if (out_f32) {  // layer 2: BN + residual (f16 NHWC) + GELU -> f32 NCHW
#pragma unroll
    for (int ot = 0; ot < 2; ot++) {
#pragma unroll
      for (int r = 0; r < 16; r++) {
        int oc = ot * 32 + (r & 3) + 8 * (r >> 2) + 4 * hi;
        float a = ot ? acc1[r] : acc0[r];
        size_t idx = ((size_t)(b * 64 + oc)) * HWSZ + y * WW + x;
        float v = a * scale[oc] + shift[oc] + h2f(ivs[ot * 4 + (r >> 2)][r & 3]);
        v = 0.5f * v * (1.f + erff(v * 0.70710678118654752f));
        out_f32[idx] = v;
      }
    }
  } else {  // layer 1: BN + GELU -> f16 NHWC
    size_t base = ((size_t)b * HWSZ + y * WW + x) * 64;
#pragma unroll
    for (int ot = 0; ot < 2; ot++) {
#pragma unroll
      for (int blk = 0; blk < 4; blk++) {
        short4v pv;
#pragma unroll
        for (int rr = 0; rr < 4; rr++) {
          int r = blk * 4 + rr;
          int oc = ot * 32 + blk * 8 + hi * 4 + rr;
          float a = ot ? acc1[r] : acc0[r];
          float v = a * scale[oc] + shift[oc];
          v = 0.5f * v * (1.f + erff(v * 0.70710678118654752f));
          pv[rr] = f2h(v);
        }
        *(short4v*)&out_cl[base + ot * 32 + blk * 8 + hi * 4] = pv;
      }
    }
  }
}

// ---------------------------------------------------------------------------
extern "C" void kernel_launch(void* const* d_in, const int* in_sizes, int n_in,
                              void* d_out, int out_size, void* d_ws, size_t ws_size,
                              hipStream_t stream) {
  const float* x     = (const float*)d_in[0];
  const float* w_om1 = (const float*)d_in[1];
  const float* b_om1 = (const float*)d_in[2];
  const float* w_d1  = (const float*)d_in[3];
  const float* bn1g  = (const float*)d_in[4];
  const float* bn1b  = (const float*)d_in[5];
  const float* bn1m  = (const float*)d_in[6];
  const float* bn1v  = (const float*)d_in[7];
  const float* w_om2 = (const float*)d_in[8];
  const float* b_om2 = (const float*)d_in[9];
  const float* w_d2  = (const float*)d_in[10];
  const float* bn2g  = (const float*)d_in[11];
  const float* bn2b  = (const float*)d_in[12];
  const float* bn2m  = (const float*)d_in[13];
  const float* bn2v  = (const float*)d_in[14];

  float* ws    = (float*)d_ws;
  float* sc    = ws;                       // 256 f
  short* w1h   = (short*)(ws + 256);       // 36864 halves
  short* w2h   = w1h + 36864;
  short* wo1h  = w2h + 36864;              // 18432 halves
  short* wo2h  = wo1h + 18432;
  short* x_cl  = (short*)(ws + 55552);     // 6,553,600 halves
  short* o1_cl = x_cl + 6553600;           // 6,553,600 halves
  float* outp  = (float*)d_out;

  pre_kernel<<<dim3(1664), dim3(256), 0, stream>>>(
      x, bn1g, bn1b, bn1m, bn1v, bn2g, bn2b, bn2m, bn2v,
      w_d1, w_d2, w_om1, w_om2, sc, w1h, w2h, wo1h, wo2h, x_cl);

  dim3 grid(WW / 16, HH / 8, 4);
  dcn_fused<<<grid, dim3(256), 0, stream>>>(
      x_cl, wo1h, b_om1, w1h, sc, sc + 64, nullptr, o1_cl, nullptr);
  dcn_fused<<<grid, dim3(256), 0, stream>>>(
      o1_cl, wo2h, b_om2, w2h, sc + 128, sc + 192, x_cl, nullptr, outp);
}

// Round 6
// 199.984 us; speedup vs baseline: 1.0678x; 1.0450x over previous
//
#include <hip/hip_runtime.h>
#include <math.h>

#define HH 160
#define WW 160
#define HWSZ 25600
#define TR 14
#define TC 22
#define NSLOT 308   // TR*TC tile slots, margin +-3 around 16x8 px tile

typedef __attribute__((ext_vector_type(8))) short short8;
typedef __attribute__((ext_vector_type(4))) short short4v;
typedef __attribute__((ext_vector_type(8))) _Float16 half8;
typedef __attribute__((ext_vector_type(2))) _Float16 half2v;
typedef __attribute__((ext_vector_type(4))) float f32x4;
typedef __attribute__((ext_vector_type(16))) float f32x16;

__device__ __forceinline__ short f2h(float f) {
  union { _Float16 h; short s; } u; u.h = (_Float16)f; return u.s;
}
__device__ __forceinline__ float h2f(short s) {
  union { _Float16 h; short s; } u; u.s = s; return (float)u.h;
}
__device__ __forceinline__ half2v bcast_h(short s) {
  unsigned int x = (unsigned short)s; x |= x << 16;
  union { unsigned int u; half2v h; } v; v.u = x; return v.h;
}

// ---------------------------------------------------------------------------
// pre: blocks [0,1600): transpose x f32 NCHW -> f16 NHWC.
//      blocks [1600,1664): BN fold + weight reorder to A-frag layouts.
// dcn w (32x32x16 A-frag): [tap9][s4][ot2][hi2][oc32][j8]
//      element (oc_g=ot*32+oc, c=s*16+hi*8+j, tap); lane l reads l*16B
//      contiguous per (s,ot) -> conflict-free 1KB wave access.
// om  w (16x16x32 A-frag): [f18][ot2][m16][q4][j8], oc>=27 zero-padded
__global__ __launch_bounds__(256) void pre_kernel(
    const float* __restrict__ x,
    const float* __restrict__ g1, const float* __restrict__ b1,
    const float* __restrict__ m1, const float* __restrict__ v1,
    const float* __restrict__ g2, const float* __restrict__ b2,
    const float* __restrict__ m2, const float* __restrict__ v2,
    const float* __restrict__ wd1, const float* __restrict__ wd2,
    const float* __restrict__ wo1, const float* __restrict__ wo2,
    float* __restrict__ sc, short* __restrict__ wd1h, short* __restrict__ wd2h,
    short* __restrict__ wo1h, short* __restrict__ wo2h,
    short* __restrict__ xcl) {
  __shared__ short tmp[64][72];
  int t = threadIdx.x;
  int bx = blockIdx.x;
  if (bx < 1600) {
    int b = bx / 400, p0 = (bx - b * 400) * 64;
    const float* xb = x + (size_t)b * 64 * HWSZ;
    for (int i = t; i < 4096; i += 256) {
      int c = i >> 6, p = i & 63;
      tmp[p][c] = f2h(xb[c * HWSZ + p0 + p]);
    }
    __syncthreads();
    short* ob = xcl + ((size_t)b * HWSZ + p0) * 64;
    for (int i = t; i < 512; i += 256) {
      int p = i >> 3, g = i & 7;
      *(short8*)&ob[p * 64 + g * 8] = *(const short8*)&tmp[p][g * 8];
    }
    return;
  }
  int i0 = (bx - 1600) * 256 + t;  // 0..16383
  for (int i = i0; i < 36864; i += 16384) {
    int j = i & 7, oc = (i >> 3) & 31, hi = (i >> 8) & 1;
    int ot = (i >> 9) & 1, s = (i >> 10) & 3, tap = i >> 12;
    int src = (ot * 32 + oc) * 576 + (s * 16 + hi * 8 + j) * 9 + tap;
    wd1h[i] = f2h(wd1[src]);
    wd2h[i] = f2h(wd2[src]);
  }
  for (int i = i0; i < 18432; i += 16384) {
    int j = i & 7, q = (i >> 3) & 3, m = (i >> 5) & 15;
    int ot = (i >> 9) & 1, f = i >> 10;
    int kp = f * 32 + q * 8 + j;
    int k = kp >> 6, c = kp & 63;
    int oc = ot * 16 + m;
    wo1h[i] = (oc < 27) ? f2h(wo1[oc * 576 + c * 9 + k]) : (short)0;
    wo2h[i] = (oc < 27) ? f2h(wo2[oc * 576 + c * 9 + k]) : (short)0;
  }
  if (i0 < 64) {
    float s1 = g1[i0] * rsqrtf(v1[i0] + 1e-5f);
    sc[i0]       = s1;
    sc[64 + i0]  = b1[i0] - m1[i0] * s1;
    float s2 = g2[i0] * rsqrtf(v2[i0] + 1e-5f);
    sc[128 + i0] = s2;
    sc[192 + i0] = b2[i0] - m2[i0] * s2;
  }
}

// ---------------------------------------------------------------------------
// dcn_fused: offset-conv (27ch) + modulated deform conv (64->64) + BN
//            + optional residual + GELU, all from one staged tile.
// Block: 16x * 8y px, 256 thr / 4 waves. Main GEMM uses 32x32x16 MFMA:
// wave w owns 32 px (rows y0+2w, y0+2w+1); B-frag px=lane&31, hi=lane>>5
// -> 2 lanes/px compute sampling meta, 8KB A panel serves 32 px.
// A panel single-buffered (2 barriers/tap, reg-prefetch k+1) in a UNION
// region that first holds the om scratch (dead after reg pull) -> LDS =
// xt 39424 + uni 10240 = 49664 B -> 3 blocks/CU = 12 waves resident.
__global__ __launch_bounds__(256, 3) void dcn_fused(
    const short* __restrict__ xcl,     // [B][HW][64] f16 NHWC
    const short* __restrict__ who,     // om weights  [f][2][16][4][8]
    const float* __restrict__ bias_om, // 27
    const short* __restrict__ whd,     // dcn weights [tap][s][ot][hi][oc][j]
    const float* __restrict__ scale, const float* __restrict__ shift,
    const short* __restrict__ id_cl,     // f16 NHWC residual or null
    short* __restrict__ out_cl,          // f16 NHWC (layer 1) or null
    float* __restrict__ out_f32) {       // f32 NCHW (layer 2) or null
  __shared__ short xt[NSLOT * 64];          // 39424 B, 16B groups swizzled
  __shared__ __align__(16) short uni[5120]; // om scratch (10240B) / A panel (8192B)

  int t = threadIdx.x;
  int x0 = blockIdx.x * 16, y0 = blockIdx.y * 8, b = blockIdx.z;
  int w = t >> 6, lane = t & 63, q = lane >> 4, m = lane & 15;
  int hi = lane >> 5, p31 = lane & 31;
  int ybase = y0 - 3, xbase = x0 - 3;

  // early-issue global loads of tap-0 A panel (8192 B / 256 thr = 32 B/thr)
  short8 pr0 = *(const short8*)&whd[t * 8];
  short8 pr1 = *(const short8*)&whd[2048 + t * 8];

  // ---- stage tile (coalesced b128 copies) ----
  const short* xb = xcl + (size_t)b * HWSZ * 64;
  for (int i = t; i < NSLOT * 8; i += 256) {
    int slot = i >> 3, g = i & 7;
    int ty = slot / TC, tx = slot - ty * TC;
    int gy = ybase + ty, gx = xbase + tx;
    short8 v = {};
    if (gy >= 0 && gy < HH && gx >= 0 && gx < WW)
      v = *(const short8*)&xb[(gy * WW + gx) * 64 + g * 8];
    *(short8*)&xt[slot * 64 + ((g ^ (slot & 7)) << 3)] = v;
  }
  __syncthreads();  // xt visible

  // ---- om GEMM (16x16x32): wave w -> 27 oc x 32 px (2 px-tiles) ----
  {
    f32x4 oacc[2][2] = {};
#pragma unroll 6
    for (int f = 0; f < 18; f++) {
      int k = f >> 1;
      int ki = k / 3, kj = k - ki * 3;
      int g = (f & 1) * 4 + q;
      const short* ap = who + (f * 128 + m * 4 + q) * 8;
      short8 a0 = *(const short8*)ap;
      short8 a1 = *(const short8*)(ap + 512);
      union { short8 s8; half8 h; } A0, A1;
      A0.s8 = a0; A1.s8 = a1;
#pragma unroll
      for (int p = 0; p < 2; p++) {
        int slotb = (w * 2 + p + ki + 2) * TC + (m + kj + 2);
        union { short8 s8; half8 h; } B;
        B.s8 = *(const short8*)&xt[slotb * 64 + ((g ^ (slotb & 7)) << 3)];
        oacc[p][0] = __builtin_amdgcn_mfma_f32_16x16x32_f16(A0.h, B.h, oacc[p][0], 0, 0, 0);
        oacc[p][1] = __builtin_amdgcn_mfma_f32_16x16x32_f16(A1.h, B.h, oacc[p][1], 0, 0, 0);
      }
    }
#pragma unroll
    for (int p = 0; p < 2; p++) {
      int px = w * 32 + p * 16 + m;
#pragma unroll
      for (int mt = 0; mt < 2; mt++) {
        short4v pv;
#pragma unroll
        for (int r = 0; r < 4; r++) {
          int oc = mt * 16 + q * 4 + r;
          float bb = (oc < 27) ? bias_om[oc] : 0.f;
          pv[r] = f2h(oacc[p][mt][r] + bb);
        }
        *(short4v*)&uni[px * 40 + mt * 16 + q * 4] = pv;  // stride 40 (16B rows)
      }
    }
  }
  __syncthreads();  // om scratch visible

  // ---- pull this lane's pixel om values (36 ch) into registers ----
  union { short s[40]; short8 v8[5]; } omr;
  {
    int px = w * 32 + p31;
#pragma unroll
    for (int i = 0; i < 5; i++)
      omr.v8[i] = *(const short8*)&uni[px * 40 + i * 8];
  }
  __syncthreads();  // all omr reads complete -> uni reusable as A panel

  // stage tap-0 panel, prefetch tap-1 to regs
  *(short8*)&uni[t * 8]        = pr0;
  *(short8*)&uni[2048 + t * 8] = pr1;
  pr0 = *(const short8*)&whd[4096 + t * 8];
  pr1 = *(const short8*)&whd[4096 + 2048 + t * 8];
  __syncthreads();  // tap-0 panel visible

  int y = y0 + w * 2 + (p31 >> 4), x = x0 + m;

  // hoist layer-2 residual load above the tap loop (hides HBM latency)
  short4v ivs[8];
  if (out_f32) {
    size_t pbase = ((size_t)b * HWSZ + y * WW + x) * 64;
#pragma unroll
    for (int ot = 0; ot < 2; ot++)
#pragma unroll
      for (int blk = 0; blk < 4; blk++)
        ivs[ot * 4 + blk] =
            *(const short4v*)&id_cl[pbase + ot * 32 + blk * 8 + hi * 4];
  }

  // ---- main GEMM (32x32x16): 64 oc x 32 px/wave, K=576 ----
  f32x16 acc0 = {}, acc1 = {};
#pragma unroll
  for (int k = 0; k < 9; ++k) {
    // inline meta for this lane's pixel (verbatim formulas)
    float dy = h2f(omr.s[2 * k]);
    float dx = h2f(omr.s[2 * k + 1]);
    float ml = h2f(omr.s[18 + k]);
    float msk = 1.f / (1.f + __expf(-ml));
    int ki = k / 3, kj = k - ki * 3;
    float py  = (float)(y - 1 + ki) + dy;
    float pxf = (float)(x - 1 + kj) + dx;
    float fy = floorf(py), fx = floorf(pxf);
    float ly = py - fy, lx = pxf - fx;
    int yi0 = (int)fy, xi0 = (int)fx;
    bool vy0 = (yi0 >= 0) & (yi0 < HH), vy1 = (yi0 + 1 >= 0) & (yi0 + 1 < HH);
    bool vx0 = (xi0 >= 0) & (xi0 < WW), vx1 = (xi0 + 1 >= 0) & (xi0 + 1 < WW);
    int ty0 = min(max(yi0 - ybase, 0), TR - 2);
    int tx0 = min(max(xi0 - xbase, 0), TC - 2);
    int p00 = ty0 * TC + tx0;
    half2v w00 = bcast_h(f2h((vy0 & vx0) ? (1.f - ly) * (1.f - lx) * msk : 0.f));
    half2v w01 = bcast_h(f2h((vy0 & vx1) ? (1.f - ly) * lx * msk : 0.f));
    half2v w10 = bcast_h(f2h((vy1 & vx0) ? ly * (1.f - lx) * msk : 0.f));
    half2v w11 = bcast_h(f2h((vy1 & vx1) ? ly * lx * msk : 0.f));
    int s00 = p00, s01 = p00 + 1, s10 = p00 + TC, s11 = p00 + TC + 1;
#pragma unroll
    for (int s = 0; s < 4; s++) {
      int g = s * 2 + hi;  // 16B ch-group this lane consumes for slice s
      union { short8 s8; half2v h[4]; } c00, c01, c10, c11, bb;
      c00.s8 = *(const short8*)&xt[s00 * 64 + ((g ^ (s00 & 7)) << 3)];
      c01.s8 = *(const short8*)&xt[s01 * 64 + ((g ^ (s01 & 7)) << 3)];
      c10.s8 = *(const short8*)&xt[s10 * 64 + ((g ^ (s10 & 7)) << 3)];
      c11.s8 = *(const short8*)&xt[s11 * 64 + ((g ^ (s11 & 7)) << 3)];
#pragma unroll
      for (int d = 0; d < 4; d++)
        bb.h[d] = c00.h[d] * w00 + c01.h[d] * w01 + c10.h[d] * w10 +
                  c11.h[d] * w11;
      // A-frags: lane l reads contiguous 16B within (s,ot) 1KB panels
      const short* ap = uni + s * 1024 + lane * 8;
      short8 a0 = *(const short8*)ap;
      short8 a1 = *(const short8*)(ap + 512);
      union { short8 s8; half8 h8; } B, A0, A1;
      B.s8 = bb.s8; A0.s8 = a0; A1.s8 = a1;
      acc0 = __builtin_amdgcn_mfma_f32_32x32x16_f16(A0.h8, B.h8, acc0, 0, 0, 0);
      acc1 = __builtin_amdgcn_mfma_f32_32x32x16_f16(A1.h8, B.h8, acc1, 0, 0, 0);
    }
    if (k < 8) {
      __syncthreads();  // all waves done reading tap-k panel
      *(short8*)&uni[t * 8]        = pr0;
      *(short8*)&uni[2048 + t * 8] = pr1;
      if (k < 7) {  // issue tap-(k+2) loads; complete during next compute
        pr0 = *(const short8*)&whd[(k + 2) * 4096 + t * 8];
        pr1 = *(const short8*)&whd[(k + 2) * 4096 + 2048 + t * 8];
      }
      __syncthreads();  // tap-(k+1) panel visible
    }
  }

  // ---- epilogue ----
  // D layout (32x32): col px = lane&31; row oc_in_tile = (r&3)+8*(r>>2)+4*hi
  if (out_f32) {  // layer 2: BN + residual (f16 NHWC) + GELU -> f32 NCHW
#pragma unroll
    for (int ot = 0; ot < 2; ot++) {
#pragma unroll
      for (int r = 0; r < 16; r++) {
        int oc = ot * 32 + (r & 3) + 8 * (r >> 2) + 4 * hi;
        float a = ot ? acc1[r] : acc0[r];
        size_t idx = ((size_t)(b * 64 + oc)) * HWSZ + y * WW + x;
        float v = a * scale[oc] + shift[oc] + h2f(ivs[ot * 4 + (r >> 2)][r & 3]);
        v = 0.5f * v * (1.f + erff(v * 0.70710678118654752f));
        out_f32[idx] = v;
      }
    }
  } else {  // layer 1: BN + GELU -> f16 NHWC
    size_t base = ((size_t)b * HWSZ + y * WW + x) * 64;
#pragma unroll
    for (int ot = 0; ot < 2; ot++) {
#pragma unroll
      for (int blk = 0; blk < 4; blk++) {
        short4v pv;
#pragma unroll
        for (int rr = 0; rr < 4; rr++) {
          int r = blk * 4 + rr;
          int oc = ot * 32 + blk * 8 + hi * 4 + rr;
          float a = ot ? acc1[r] : acc0[r];
          float v = a * scale[oc] + shift[oc];
          v = 0.5f * v * (1.f + erff(v * 0.70710678118654752f));
          pv[rr] = f2h(v);
        }
        *(short4v*)&out_cl[base + ot * 32 + blk * 8 + hi * 4] = pv;
      }
    }
  }
}

// ---------------------------------------------------------------------------
extern "C" void kernel_launch(void* const* d_in, const int* in_sizes, int n_in,
                              void* d_out, int out_size, void* d_ws, size_t ws_size,
                              hipStream_t stream) {
  const float* x     = (const float*)d_in[0];
  const float* w_om1 = (const float*)d_in[1];
  const float* b_om1 = (const float*)d_in[2];
  const float* w_d1  = (const float*)d_in[3];
  const float* bn1g  = (const float*)d_in[4];
  const float* bn1b  = (const float*)d_in[5];
  const float* bn1m  = (const float*)d_in[6];
  const float* bn1v  = (const float*)d_in[7];
  const float* w_om2 = (const float*)d_in[8];
  const float* b_om2 = (const float*)d_in[9];
  const float* w_d2  = (const float*)d_in[10];
  const float* bn2g  = (const float*)d_in[11];
  const float* bn2b  = (const float*)d_in[12];
  const float* bn2m  = (const float*)d_in[13];
  const float* bn2v  = (const float*)d_in[14];

  float* ws    = (float*)d_ws;
  float* sc    = ws;                       // 256 f
  short* w1h   = (short*)(ws + 256);       // 36864 halves
  short* w2h   = w1h + 36864;
  short* wo1h  = w2h + 36864;              // 18432 halves
  short* wo2h  = wo1h + 18432;
  short* x_cl  = (short*)(ws + 55552);     // 6,553,600 halves
  short* o1_cl = x_cl + 6553600;           // 6,553,600 halves
  float* outp  = (float*)d_out;

  pre_kernel<<<dim3(1664), dim3(256), 0, stream>>>(
      x, bn1g, bn1b, bn1m, bn1v, bn2g, bn2b, bn2m, bn2v,
      w_d1, w_d2, w_om1, w_om2, sc, w1h, w2h, wo1h, wo2h, x_cl);

  dim3 grid(WW / 16, HH / 8, 4);
  dcn_fused<<<grid, dim3(256), 0, stream>>>(
      x_cl, wo1h, b_om1, w1h, sc, sc + 64, nullptr, o1_cl, nullptr);
  dcn_fused<<<grid, dim3(256), 0, stream>>>(
      o1_cl, wo2h, b_om2, w2h, sc + 128, sc + 192, x_cl, nullptr, outp);
}

// Round 7
// 196.249 us; speedup vs baseline: 1.0881x; 1.0190x over previous
//
#include <hip/hip_runtime.h>
#include <math.h>

#define HH 160
#define WW 160
#define HWSZ 25600
#define TR 14
#define TC 22
#define NSLOT 308   // TR*TC tile slots, margin +-3 around 16x8 px tile

typedef __attribute__((ext_vector_type(8))) short short8;
typedef __attribute__((ext_vector_type(4))) short short4v;
typedef __attribute__((ext_vector_type(8))) _Float16 half8;
typedef __attribute__((ext_vector_type(2))) _Float16 half2v;
typedef __attribute__((ext_vector_type(4))) float f32x4;
typedef __attribute__((ext_vector_type(16))) float f32x16;

__device__ __forceinline__ short f2h(float f) {
  union { _Float16 h; short s; } u; u.h = (_Float16)f; return u.s;
}
__device__ __forceinline__ float h2f(short s) {
  union { _Float16 h; short s; } u; u.s = s; return (float)u.h;
}
__device__ __forceinline__ half2v bcast_h(short s) {
  unsigned int x = (unsigned short)s; x |= x << 16;
  union { unsigned int u; half2v h; } v; v.u = x; return v.h;
}

// ---------------------------------------------------------------------------
// pre: blocks [0,1600): transpose x f32 NCHW -> f16 NHWC.
//      blocks [1600,1664): BN fold + weight reorder to A-frag layouts.
// dcn w (32x32x16 A-frag): [tap9][s4][ot2][hi2][oc32][j8]
//      element (oc_g=ot*32+oc, c=s*16+hi*8+j, tap); lane l reads l*16B
//      contiguous per (s,ot) -> fully coalesced 1KB wave access.
// om  w (16x16x32 A-frag): [f18][ot2][m16][q4][j8], oc>=27 zero-padded
__global__ __launch_bounds__(256) void pre_kernel(
    const float* __restrict__ x,
    const float* __restrict__ g1, const float* __restrict__ b1,
    const float* __restrict__ m1, const float* __restrict__ v1,
    const float* __restrict__ g2, const float* __restrict__ b2,
    const float* __restrict__ m2, const float* __restrict__ v2,
    const float* __restrict__ wd1, const float* __restrict__ wd2,
    const float* __restrict__ wo1, const float* __restrict__ wo2,
    float* __restrict__ sc, short* __restrict__ wd1h, short* __restrict__ wd2h,
    short* __restrict__ wo1h, short* __restrict__ wo2h,
    short* __restrict__ xcl) {
  __shared__ short tmp[64][72];
  int t = threadIdx.x;
  int bx = blockIdx.x;
  if (bx < 1600) {
    int b = bx / 400, p0 = (bx - b * 400) * 64;
    const float* xb = x + (size_t)b * 64 * HWSZ;
    for (int i = t; i < 4096; i += 256) {
      int c = i >> 6, p = i & 63;
      tmp[p][c] = f2h(xb[c * HWSZ + p0 + p]);
    }
    __syncthreads();
    short* ob = xcl + ((size_t)b * HWSZ + p0) * 64;
    for (int i = t; i < 512; i += 256) {
      int p = i >> 3, g = i & 7;
      *(short8*)&ob[p * 64 + g * 8] = *(const short8*)&tmp[p][g * 8];
    }
    return;
  }
  int i0 = (bx - 1600) * 256 + t;  // 0..16383
  for (int i = i0; i < 36864; i += 16384) {
    int j = i & 7, oc = (i >> 3) & 31, hi = (i >> 8) & 1;
    int ot = (i >> 9) & 1, s = (i >> 10) & 3, tap = i >> 12;
    int src = (ot * 32 + oc) * 576 + (s * 16 + hi * 8 + j) * 9 + tap;
    wd1h[i] = f2h(wd1[src]);
    wd2h[i] = f2h(wd2[src]);
  }
  for (int i = i0; i < 18432; i += 16384) {
    int j = i & 7, q = (i >> 3) & 3, m = (i >> 5) & 15;
    int ot = (i >> 9) & 1, f = i >> 10;
    int kp = f * 32 + q * 8 + j;
    int k = kp >> 6, c = kp & 63;
    int oc = ot * 16 + m;
    wo1h[i] = (oc < 27) ? f2h(wo1[oc * 576 + c * 9 + k]) : (short)0;
    wo2h[i] = (oc < 27) ? f2h(wo2[oc * 576 + c * 9 + k]) : (short)0;
  }
  if (i0 < 64) {
    float s1 = g1[i0] * rsqrtf(v1[i0] + 1e-5f);
    sc[i0]       = s1;
    sc[64 + i0]  = b1[i0] - m1[i0] * s1;
    float s2 = g2[i0] * rsqrtf(v2[i0] + 1e-5f);
    sc[128 + i0] = s2;
    sc[192 + i0] = b2[i0] - m2[i0] * s2;
  }
}

// ---------------------------------------------------------------------------
// dcn_fused: offset-conv (27ch) + modulated deform conv (64->64) + BN
//            + optional residual + GELU, all from one staged tile.
// Block: 16x * 8y px, 256 thr / 4 waves. Main GEMM uses 32x32x16 MFMA:
// wave w owns 32 px (rows y0+2w, y0+2w+1); 2 lanes/px compute meta.
// A-fragments read DIRECTLY from global in the tap loop (whd is 72 KB,
// L1/L2-resident; 230 MB/dispatch of coalesced L2 traffic ~ 7 us of L2 BW)
// -> the 9-tap loop is BARRIER-FREE: no LDS writes, no staging, fully
// unrolled; 12 resident waves slip freely and hide all latency.
// 2 barriers per block total (post-xt-stage, post-om-scratch).
// LDS = xt 39424 + oms 10240 = 49664 B -> 3 blocks/CU = 12 waves.
__global__ __launch_bounds__(256, 3) void dcn_fused(
    const short* __restrict__ xcl,     // [B][HW][64] f16 NHWC
    const short* __restrict__ who,     // om weights  [f][2][16][4][8]
    const float* __restrict__ bias_om, // 27
    const short* __restrict__ whd,     // dcn weights [tap][s][ot][hi][oc][j]
    const float* __restrict__ scale, const float* __restrict__ shift,
    const short* __restrict__ id_cl,     // f16 NHWC residual or null
    short* __restrict__ out_cl,          // f16 NHWC (layer 1) or null
    float* __restrict__ out_f32) {       // f32 NCHW (layer 2) or null
  __shared__ short xt[NSLOT * 64];          // 39424 B, 16B groups swizzled
  __shared__ __align__(16) short oms[5120]; // om scratch (10240 B)

  int t = threadIdx.x;
  int x0 = blockIdx.x * 16, y0 = blockIdx.y * 8, b = blockIdx.z;
  int w = t >> 6, lane = t & 63, q = lane >> 4, m = lane & 15;
  int hi = lane >> 5, p31 = lane & 31;
  int ybase = y0 - 3, xbase = x0 - 3;

  // ---- stage tile (coalesced b128 copies) ----
  const short* xb = xcl + (size_t)b * HWSZ * 64;
  for (int i = t; i < NSLOT * 8; i += 256) {
    int slot = i >> 3, g = i & 7;
    int ty = slot / TC, tx = slot - ty * TC;
    int gy = ybase + ty, gx = xbase + tx;
    short8 v = {};
    if (gy >= 0 && gy < HH && gx >= 0 && gx < WW)
      v = *(const short8*)&xb[(gy * WW + gx) * 64 + g * 8];
    *(short8*)&xt[slot * 64 + ((g ^ (slot & 7)) << 3)] = v;
  }
  __syncthreads();  // xt visible

  // ---- om GEMM (16x16x32): wave w -> 27 oc x 32 px (2 px-tiles) ----
  {
    f32x4 oacc[2][2] = {};
#pragma unroll 6
    for (int f = 0; f < 18; f++) {
      int k = f >> 1;
      int ki = k / 3, kj = k - ki * 3;
      int g = (f & 1) * 4 + q;
      const short* ap = who + (f * 128 + m * 4 + q) * 8;
      short8 a0 = *(const short8*)ap;
      short8 a1 = *(const short8*)(ap + 512);
      union { short8 s8; half8 h; } A0, A1;
      A0.s8 = a0; A1.s8 = a1;
#pragma unroll
      for (int p = 0; p < 2; p++) {
        int slotb = (w * 2 + p + ki + 2) * TC + (m + kj + 2);
        union { short8 s8; half8 h; } B;
        B.s8 = *(const short8*)&xt[slotb * 64 + ((g ^ (slotb & 7)) << 3)];
        oacc[p][0] = __builtin_amdgcn_mfma_f32_16x16x32_f16(A0.h, B.h, oacc[p][0], 0, 0, 0);
        oacc[p][1] = __builtin_amdgcn_mfma_f32_16x16x32_f16(A1.h, B.h, oacc[p][1], 0, 0, 0);
      }
    }
#pragma unroll
    for (int p = 0; p < 2; p++) {
      int px = w * 32 + p * 16 + m;
#pragma unroll
      for (int mt = 0; mt < 2; mt++) {
        short4v pv;
#pragma unroll
        for (int r = 0; r < 4; r++) {
          int oc = mt * 16 + q * 4 + r;
          float bb = (oc < 27) ? bias_om[oc] : 0.f;
          pv[r] = f2h(oacc[p][mt][r] + bb);
        }
        *(short4v*)&oms[px * 40 + mt * 16 + q * 4] = pv;  // stride 40 (16B rows)
      }
    }
  }
  __syncthreads();  // oms visible (never overwritten afterwards)

  // ---- pull this lane's pixel om values (36 ch) into registers ----
  union { short s[40]; short8 v8[5]; } omr;
  {
    int px = w * 32 + p31;
#pragma unroll
    for (int i = 0; i < 5; i++)
      omr.v8[i] = *(const short8*)&oms[px * 40 + i * 8];
  }

  int y = y0 + w * 2 + (p31 >> 4), x = x0 + m;

  // hoist layer-2 residual load above the tap loop (hides HBM latency)
  short4v ivs[8];
  if (out_f32) {
    size_t pbase = ((size_t)b * HWSZ + y * WW + x) * 64;
#pragma unroll
    for (int ot = 0; ot < 2; ot++)
#pragma unroll
      for (int blk = 0; blk < 4; blk++)
        ivs[ot * 4 + blk] =
            *(const short4v*)&id_cl[pbase + ot * 32 + blk * 8 + hi * 4];
  }

  // ---- main GEMM (32x32x16): 64 oc x 32 px/wave, K=576; barrier-free ----
  f32x16 acc0 = {}, acc1 = {};
#pragma unroll
  for (int k = 0; k < 9; ++k) {
    // inline meta for this lane's pixel (verbatim formulas)
    float dy = h2f(omr.s[2 * k]);
    float dx = h2f(omr.s[2 * k + 1]);
    float ml = h2f(omr.s[18 + k]);
    float msk = 1.f / (1.f + __expf(-ml));
    int ki = k / 3, kj = k - ki * 3;
    float py  = (float)(y - 1 + ki) + dy;
    float pxf = (float)(x - 1 + kj) + dx;
    float fy = floorf(py), fx = floorf(pxf);
    float ly = py - fy, lx = pxf - fx;
    int yi0 = (int)fy, xi0 = (int)fx;
    bool vy0 = (yi0 >= 0) & (yi0 < HH), vy1 = (yi0 + 1 >= 0) & (yi0 + 1 < HH);
    bool vx0 = (xi0 >= 0) & (xi0 < WW), vx1 = (xi0 + 1 >= 0) & (xi0 + 1 < WW);
    int ty0 = min(max(yi0 - ybase, 0), TR - 2);
    int tx0 = min(max(xi0 - xbase, 0), TC - 2);
    int p00 = ty0 * TC + tx0;
    half2v w00 = bcast_h(f2h((vy0 & vx0) ? (1.f - ly) * (1.f - lx) * msk : 0.f));
    half2v w01 = bcast_h(f2h((vy0 & vx1) ? (1.f - ly) * lx * msk : 0.f));
    half2v w10 = bcast_h(f2h((vy1 & vx0) ? ly * (1.f - lx) * msk : 0.f));
    half2v w11 = bcast_h(f2h((vy1 & vx1) ? ly * lx * msk : 0.f));
    int s00 = p00, s01 = p00 + 1, s10 = p00 + TC, s11 = p00 + TC + 1;
#pragma unroll
    for (int s = 0; s < 4; s++) {
      int g = s * 2 + hi;  // 16B ch-group this lane consumes for slice s
      union { short8 s8; half2v h[4]; } c00, c01, c10, c11, bb;
      c00.s8 = *(const short8*)&xt[s00 * 64 + ((g ^ (s00 & 7)) << 3)];
      c01.s8 = *(const short8*)&xt[s01 * 64 + ((g ^ (s01 & 7)) << 3)];
      c10.s8 = *(const short8*)&xt[s10 * 64 + ((g ^ (s10 & 7)) << 3)];
      c11.s8 = *(const short8*)&xt[s11 * 64 + ((g ^ (s11 & 7)) << 3)];
#pragma unroll
      for (int d = 0; d < 4; d++)
        bb.h[d] = c00.h[d] * w00 + c01.h[d] * w01 + c10.h[d] * w10 +
                  c11.h[d] * w11;
      // A-frags straight from global: wave reads 1KB contiguous per load,
      // whd panel is L1/L2-resident (72 KB, shared by all blocks)
      const short* ap = whd + k * 4096 + s * 1024 + lane * 8;
      short8 a0 = *(const short8*)ap;
      short8 a1 = *(const short8*)(ap + 512);
      union { short8 s8; half8 h8; } B, A0, A1;
      B.s8 = bb.s8; A0.s8 = a0; A1.s8 = a1;
      acc0 = __builtin_amdgcn_mfma_f32_32x32x16_f16(A0.h8, B.h8, acc0, 0, 0, 0);
      acc1 = __builtin_amdgcn_mfma_f32_32x32x16_f16(A1.h8, B.h8, acc1, 0, 0, 0);
    }
  }

  // ---- epilogue ----
  // D layout (32x32): col px = lane&31; row oc_in_tile = (r&3)+8*(r>>2)+4*hi
  if (out_f32) {  // layer 2: BN + residual (f16 NHWC) + GELU -> f32 NCHW
#pragma unroll
    for (int ot = 0; ot < 2; ot++) {
#pragma unroll
      for (int r = 0; r < 16; r++) {
        int oc = ot * 32 + (r & 3) + 8 * (r >> 2) + 4 * hi;
        float a = ot ? acc1[r] : acc0[r];
        size_t idx = ((size_t)(b * 64 + oc)) * HWSZ + y * WW + x;
        float v = a * scale[oc] + shift[oc] + h2f(ivs[ot * 4 + (r >> 2)][r & 3]);
        v = 0.5f * v * (1.f + erff(v * 0.70710678118654752f));
        out_f32[idx] = v;
      }
    }
  } else {  // layer 1: BN + GELU -> f16 NHWC
    size_t base = ((size_t)b * HWSZ + y * WW + x) * 64;
#pragma unroll
    for (int ot = 0; ot < 2; ot++) {
#pragma unroll
      for (int blk = 0; blk < 4; blk++) {
        short4v pv;
#pragma unroll
        for (int rr = 0; rr < 4; rr++) {
          int r = blk * 4 + rr;
          int oc = ot * 32 + blk * 8 + hi * 4 + rr;
          float a = ot ? acc1[r] : acc0[r];
          float v = a * scale[oc] + shift[oc];
          v = 0.5f * v * (1.f + erff(v * 0.70710678118654752f));
          pv[rr] = f2h(v);
        }
        *(short4v*)&out_cl[base + ot * 32 + blk * 8 + hi * 4] = pv;
      }
    }
  }
}

// ---------------------------------------------------------------------------
extern "C" void kernel_launch(void* const* d_in, const int* in_sizes, int n_in,
                              void* d_out, int out_size, void* d_ws, size_t ws_size,
                              hipStream_t stream) {
  const float* x     = (const float*)d_in[0];
  const float* w_om1 = (const float*)d_in[1];
  const float* b_om1 = (const float*)d_in[2];
  const float* w_d1  = (const float*)d_in[3];
  const float* bn1g  = (const float*)d_in[4];
  const float* bn1b  = (const float*)d_in[5];
  const float* bn1m  = (const float*)d_in[6];
  const float* bn1v  = (const float*)d_in[7];
  const float* w_om2 = (const float*)d_in[8];
  const float* b_om2 = (const float*)d_in[9];
  const float* w_d2  = (const float*)d_in[10];
  const float* bn2g  = (const float*)d_in[11];
  const float* bn2b  = (const float*)d_in[12];
  const float* bn2m  = (const float*)d_in[13];
  const float* bn2v  = (const float*)d_in[14];

  float* ws    = (float*)d_ws;
  float* sc    = ws;                       // 256 f
  short* w1h   = (short*)(ws + 256);       // 36864 halves
  short* w2h   = w1h + 36864;
  short* wo1h  = w2h + 36864;              // 18432 halves
  short* wo2h  = wo1h + 18432;
  short* x_cl  = (short*)(ws + 55552);     // 6,553,600 halves
  short* o1_cl = x_cl + 6553600;           // 6,553,600 halves
  float* outp  = (float*)d_out;

  pre_kernel<<<dim3(1664), dim3(256), 0, stream>>>(
      x, bn1g, bn1b, bn1m, bn1v, bn2g, bn2b, bn2m, bn2v,
      w_d1, w_d2, w_om1, w_om2, sc, w1h, w2h, wo1h, wo2h, x_cl);

  dim3 grid(WW / 16, HH / 8, 4);
  dcn_fused<<<grid, dim3(256), 0, stream>>>(
      x_cl, wo1h, b_om1, w1h, sc, sc + 64, nullptr, o1_cl, nullptr);
  dcn_fused<<<grid, dim3(256), 0, stream>>>(
      o1_cl, wo2h, b_om2, w2h, sc + 128, sc + 192, x_cl, nullptr, outp);
}

// Round 8
// 183.219 us; speedup vs baseline: 1.1655x; 1.0711x over previous
//
#include <hip/hip_runtime.h>
#include <math.h>

#define HH 160
#define WW 160
#define HWSZ 25600
#define TR 14
#define TC 22
#define NSLOT 308   // TR*TC tile slots, margin +-3 around 16x8 px tile

typedef __attribute__((ext_vector_type(8))) short short8;
typedef __attribute__((ext_vector_type(4))) short short4v;
typedef __attribute__((ext_vector_type(8))) _Float16 half8;
typedef __attribute__((ext_vector_type(2))) _Float16 half2v;
typedef __attribute__((ext_vector_type(4))) float f32x4;
typedef __attribute__((ext_vector_type(16))) float f32x16;
typedef __attribute__((ext_vector_type(2))) unsigned int uint2v;

__device__ __forceinline__ short f2h(float f) {
  union { _Float16 h; short s; } u; u.h = (_Float16)f; return u.s;
}
__device__ __forceinline__ float h2f(short s) {
  union { _Float16 h; short s; } u; u.s = s; return (float)u.h;
}
__device__ __forceinline__ half2v bcast_h(short s) {
  unsigned int x = (unsigned short)s; x |= x << 16;
  union { unsigned int u; half2v h; } v; v.u = x; return v.h;
}

// ---------------------------------------------------------------------------
// pre: blocks [0,1600): transpose x f32 NCHW -> f16 NHWC.
//      blocks [1600,1664): BN fold + weight reorder to A-frag layouts.
// dcn w (32x32x16 A-frag): [tap9][s4][ot2][hi2][oc32][j8]
//      element (oc_g=ot*32+oc, c=s*16+hi*8+j, tap); lane l reads l*16B
//      contiguous per (s,ot) -> fully coalesced 1KB wave access.
// om  w (32x32x16 A-frag): [kk36=tap*4+s][hi2][oc32][j8], oc>=27 zeroed;
//      same K-order (c=s*16+hi*8+j) so B-frag reads match the main loop.
__global__ __launch_bounds__(256) void pre_kernel(
    const float* __restrict__ x,
    const float* __restrict__ g1, const float* __restrict__ b1,
    const float* __restrict__ m1, const float* __restrict__ v1,
    const float* __restrict__ g2, const float* __restrict__ b2,
    const float* __restrict__ m2, const float* __restrict__ v2,
    const float* __restrict__ wd1, const float* __restrict__ wd2,
    const float* __restrict__ wo1, const float* __restrict__ wo2,
    float* __restrict__ sc, short* __restrict__ wd1h, short* __restrict__ wd2h,
    short* __restrict__ wo1h, short* __restrict__ wo2h,
    short* __restrict__ xcl) {
  __shared__ short tmp[64][72];
  int t = threadIdx.x;
  int bx = blockIdx.x;
  if (bx < 1600) {
    int b = bx / 400, p0 = (bx - b * 400) * 64;
    const float* xb = x + (size_t)b * 64 * HWSZ;
    for (int i = t; i < 4096; i += 256) {
      int c = i >> 6, p = i & 63;
      tmp[p][c] = f2h(xb[c * HWSZ + p0 + p]);
    }
    __syncthreads();
    short* ob = xcl + ((size_t)b * HWSZ + p0) * 64;
    for (int i = t; i < 512; i += 256) {
      int p = i >> 3, g = i & 7;
      *(short8*)&ob[p * 64 + g * 8] = *(const short8*)&tmp[p][g * 8];
    }
    return;
  }
  int i0 = (bx - 1600) * 256 + t;  // 0..16383
  for (int i = i0; i < 36864; i += 16384) {
    int j = i & 7, oc = (i >> 3) & 31, hi = (i >> 8) & 1;
    int ot = (i >> 9) & 1, s = (i >> 10) & 3, tap = i >> 12;
    int src = (ot * 32 + oc) * 576 + (s * 16 + hi * 8 + j) * 9 + tap;
    wd1h[i] = f2h(wd1[src]);
    wd2h[i] = f2h(wd2[src]);
  }
  for (int i = i0; i < 18432; i += 16384) {
    int j = i & 7, oc = (i >> 3) & 31, hi = (i >> 8) & 1;
    int s = (i >> 9) & 3, tap = i >> 11;
    int src = oc * 576 + (s * 16 + hi * 8 + j) * 9 + tap;
    wo1h[i] = (oc < 27) ? f2h(wo1[src]) : (short)0;
    wo2h[i] = (oc < 27) ? f2h(wo2[src]) : (short)0;
  }
  if (i0 < 64) {
    float s1 = g1[i0] * rsqrtf(v1[i0] + 1e-5f);
    sc[i0]       = s1;
    sc[64 + i0]  = b1[i0] - m1[i0] * s1;
    float s2 = g2[i0] * rsqrtf(v2[i0] + 1e-5f);
    sc[128 + i0] = s2;
    sc[192 + i0] = b2[i0] - m2[i0] * s2;
  }
}

// ---------------------------------------------------------------------------
// dcn_fused: offset-conv (27ch) + modulated deform conv (64->64) + BN
//            + optional residual + GELU, all from one staged tile.
// Block: 16x * 8y px, 256 thr / 4 waves, all GEMMs 32x32x16.
// om GEMM's D column = owner pixel lane -> om results land IN the lane
// that consumes them; the missing oc-half is fetched from lane^32 via
// permlane32_swap (wave-uniform channel registers, no LDS scratch).
// A-fragments (both GEMMs) read directly from global (72+18 KB, L1/L2-
// resident, coalesced 1KB/wave) -> whole kernel has ONE barrier.
// LDS = xt only (39424 B) -> 4 blocks/CU = 16 waves; grid 800 <= 1024
// capacity so the entire dispatch is co-resident.
__global__ __launch_bounds__(256, 4) void dcn_fused(
    const short* __restrict__ xcl,     // [B][HW][64] f16 NHWC
    const short* __restrict__ who,     // om weights  [kk36][hi2][oc32][j8]
    const float* __restrict__ bias_om, // 27
    const short* __restrict__ whd,     // dcn weights [tap][s][ot][hi][oc][j]
    const float* __restrict__ scale, const float* __restrict__ shift,
    const short* __restrict__ id_cl,     // f16 NHWC residual or null
    short* __restrict__ out_cl,          // f16 NHWC (layer 1) or null
    float* __restrict__ out_f32) {       // f32 NCHW (layer 2) or null
  __shared__ short xt[NSLOT * 64];          // 39424 B, 16B groups swizzled

  int t = threadIdx.x;
  int x0 = blockIdx.x * 16, y0 = blockIdx.y * 8, b = blockIdx.z;
  int w = t >> 6, lane = t & 63, m = lane & 15;
  int hi = lane >> 5, p31 = lane & 31;
  int ybase = y0 - 3, xbase = x0 - 3;

  // ---- stage tile (coalesced b128 copies) ----
  const short* xb = xcl + (size_t)b * HWSZ * 64;
  for (int i = t; i < NSLOT * 8; i += 256) {
    int slot = i >> 3, g = i & 7;
    int ty = slot / TC, tx = slot - ty * TC;
    int gy = ybase + ty, gx = xbase + tx;
    short8 v = {};
    if (gy >= 0 && gy < HH && gx >= 0 && gx < WW)
      v = *(const short8*)&xb[(gy * WW + gx) * 64 + g * 8];
    *(short8*)&xt[slot * 64 + ((g ^ (slot & 7)) << 3)] = v;
  }
  __syncthreads();  // xt visible -- the ONLY barrier

  // ---- om GEMM (32x32x16): 27 oc x 32 px per wave, D col = own pixel ----
  // lane holds oc = (r&3)+8*(r>>2)+4*hi for its own px; partner lane^32
  // holds the complementary 16 -> permlane32_swap exchange, no LDS.
  union { short s[32]; unsigned int u[16]; } omr;
  {
    f32x16 oacc = {};
#pragma unroll
    for (int k9 = 0; k9 < 9; k9++) {
      int ki = k9 / 3, kj = k9 - ki * 3;
      int slotb = (w * 2 + (p31 >> 4) + ki + 2) * TC + ((p31 & 15) + kj + 2);
#pragma unroll
      for (int s = 0; s < 4; s++) {
        int g = s * 2 + hi;
        union { short8 s8; half8 h; } A, B;
        B.s8 = *(const short8*)&xt[slotb * 64 + ((g ^ (slotb & 7)) << 3)];
        A.s8 = *(const short8*)&who[((k9 * 4 + s) * 64 + lane) * 8];
        oacc = __builtin_amdgcn_mfma_f32_32x32x16_f16(A.h, B.h, oacc, 0, 0, 0);
      }
    }
#pragma unroll
    for (int j = 0; j < 8; j++) {
      int c0 = 2 * (j & 1) + 8 * (j >> 1);  // channel pair base for hi=0
      int oc0 = c0 + 4 * hi;                // this lane's oc for r=2j
      float b0 = (oc0 < 27) ? bias_om[oc0] : 0.f;
      float b1 = (oc0 + 1 < 27) ? bias_om[oc0 + 1] : 0.f;
      union { unsigned int u; short s2[2]; } pk;
      pk.s2[0] = f2h(oacc[2 * j] + b0);
      pk.s2[1] = f2h(oacc[2 * j + 1] + b1);
      uint2v sw = __builtin_amdgcn_permlane32_swap(pk.u, pk.u, false, false);
      // sw[0]: lower lanes own / upper lanes partner -> channels (c0,c0+1)
      // uniformly across the wave; sw[1]: channels (c0+4,c0+5).
      omr.u[c0 >> 1]       = sw[0];
      omr.u[(c0 + 4) >> 1] = sw[1];
    }
  }

  int y = y0 + w * 2 + (p31 >> 4), x = x0 + m;

  // hoist layer-2 residual load above the tap loop (hides HBM latency)
  short4v ivs[8];
  if (out_f32) {
    size_t pbase = ((size_t)b * HWSZ + y * WW + x) * 64;
#pragma unroll
    for (int ot = 0; ot < 2; ot++)
#pragma unroll
      for (int blk = 0; blk < 4; blk++)
        ivs[ot * 4 + blk] =
            *(const short4v*)&id_cl[pbase + ot * 32 + blk * 8 + hi * 4];
  }

  // ---- main GEMM (32x32x16): 64 oc x 32 px/wave, K=576; barrier-free ----
  f32x16 acc0 = {}, acc1 = {};
#pragma unroll
  for (int k = 0; k < 9; ++k) {
    // inline meta for this lane's pixel (verbatim formulas)
    float dy = h2f(omr.s[2 * k]);
    float dx = h2f(omr.s[2 * k + 1]);
    float ml = h2f(omr.s[18 + k]);
    float msk = 1.f / (1.f + __expf(-ml));
    int ki = k / 3, kj = k - ki * 3;
    float py  = (float)(y - 1 + ki) + dy;
    float pxf = (float)(x - 1 + kj) + dx;
    float fy = floorf(py), fx = floorf(pxf);
    float ly = py - fy, lx = pxf - fx;
    int yi0 = (int)fy, xi0 = (int)fx;
    bool vy0 = (yi0 >= 0) & (yi0 < HH), vy1 = (yi0 + 1 >= 0) & (yi0 + 1 < HH);
    bool vx0 = (xi0 >= 0) & (xi0 < WW), vx1 = (xi0 + 1 >= 0) & (xi0 + 1 < WW);
    int ty0 = min(max(yi0 - ybase, 0), TR - 2);
    int tx0 = min(max(xi0 - xbase, 0), TC - 2);
    int p00 = ty0 * TC + tx0;
    half2v w00 = bcast_h(f2h((vy0 & vx0) ? (1.f - ly) * (1.f - lx) * msk : 0.f));
    half2v w01 = bcast_h(f2h((vy0 & vx1) ? (1.f - ly) * lx * msk : 0.f));
    half2v w10 = bcast_h(f2h((vy1 & vx0) ? ly * (1.f - lx) * msk : 0.f));
    half2v w11 = bcast_h(f2h((vy1 & vx1) ? ly * lx * msk : 0.f));
    int s00 = p00, s01 = p00 + 1, s10 = p00 + TC, s11 = p00 + TC + 1;
#pragma unroll
    for (int s = 0; s < 4; s++) {
      int g = s * 2 + hi;  // 16B ch-group this lane consumes for slice s
      union { short8 s8; half2v h[4]; } c00, c01, c10, c11, bb;
      c00.s8 = *(const short8*)&xt[s00 * 64 + ((g ^ (s00 & 7)) << 3)];
      c01.s8 = *(const short8*)&xt[s01 * 64 + ((g ^ (s01 & 7)) << 3)];
      c10.s8 = *(const short8*)&xt[s10 * 64 + ((g ^ (s10 & 7)) << 3)];
      c11.s8 = *(const short8*)&xt[s11 * 64 + ((g ^ (s11 & 7)) << 3)];
#pragma unroll
      for (int d = 0; d < 4; d++)
        bb.h[d] = c00.h[d] * w00 + c01.h[d] * w01 + c10.h[d] * w10 +
                  c11.h[d] * w11;
      // A-frags straight from global: wave reads 1KB contiguous per load,
      // whd panel is L1/L2-resident (72 KB, shared by all blocks)
      const short* ap = whd + k * 4096 + s * 1024 + lane * 8;
      short8 a0 = *(const short8*)ap;
      short8 a1 = *(const short8*)(ap + 512);
      union { short8 s8; half8 h8; } B, A0, A1;
      B.s8 = bb.s8; A0.s8 = a0; A1.s8 = a1;
      acc0 = __builtin_amdgcn_mfma_f32_32x32x16_f16(A0.h8, B.h8, acc0, 0, 0, 0);
      acc1 = __builtin_amdgcn_mfma_f32_32x32x16_f16(A1.h8, B.h8, acc1, 0, 0, 0);
    }
  }

  // ---- epilogue ----
  // D layout (32x32): col px = lane&31; row oc_in_tile = (r&3)+8*(r>>2)+4*hi
  if (out_f32) {  // layer 2: BN + residual (f16 NHWC) + GELU -> f32 NCHW
#pragma unroll
    for (int ot = 0; ot < 2; ot++) {
#pragma unroll
      for (int r = 0; r < 16; r++) {
        int oc = ot * 32 + (r & 3) + 8 * (r >> 2) + 4 * hi;
        float a = ot ? acc1[r] : acc0[r];
        size_t idx = ((size_t)(b * 64 + oc)) * HWSZ + y * WW + x;
        float v = a * scale[oc] + shift[oc] + h2f(ivs[ot * 4 + (r >> 2)][r & 3]);
        v = 0.5f * v * (1.f + erff(v * 0.70710678118654752f));
        out_f32[idx] = v;
      }
    }
  } else {  // layer 1: BN + GELU -> f16 NHWC
    size_t base = ((size_t)b * HWSZ + y * WW + x) * 64;
#pragma unroll
    for (int ot = 0; ot < 2; ot++) {
#pragma unroll
      for (int blk = 0; blk < 4; blk++) {
        short4v pv;
#pragma unroll
        for (int rr = 0; rr < 4; rr++) {
          int r = blk * 4 + rr;
          int oc = ot * 32 + blk * 8 + hi * 4 + rr;
          float a = ot ? acc1[r] : acc0[r];
          float v = a * scale[oc] + shift[oc];
          v = 0.5f * v * (1.f + erff(v * 0.70710678118654752f));
          pv[rr] = f2h(v);
        }
        *(short4v*)&out_cl[base + ot * 32 + blk * 8 + hi * 4] = pv;
      }
    }
  }
}

// ---------------------------------------------------------------------------
extern "C" void kernel_launch(void* const* d_in, const int* in_sizes, int n_in,
                              void* d_out, int out_size, void* d_ws, size_t ws_size,
                              hipStream_t stream) {
  const float* x     = (const float*)d_in[0];
  const float* w_om1 = (const float*)d_in[1];
  const float* b_om1 = (const float*)d_in[2];
  const float* w_d1  = (const float*)d_in[3];
  const float* bn1g  = (const float*)d_in[4];
  const float* bn1b  = (const float*)d_in[5];
  const float* bn1m  = (const float*)d_in[6];
  const float* bn1v  = (const float*)d_in[7];
  const float* w_om2 = (const float*)d_in[8];
  const float* b_om2 = (const float*)d_in[9];
  const float* w_d2  = (const float*)d_in[10];
  const float* bn2g  = (const float*)d_in[11];
  const float* bn2b  = (const float*)d_in[12];
  const float* bn2m  = (const float*)d_in[13];
  const float* bn2v  = (const float*)d_in[14];

  float* ws    = (float*)d_ws;
  float* sc    = ws;                       // 256 f
  short* w1h   = (short*)(ws + 256);       // 36864 halves
  short* w2h   = w1h + 36864;
  short* wo1h  = w2h + 36864;              // 18432 halves
  short* wo2h  = wo1h + 18432;
  short* x_cl  = (short*)(ws + 55552);     // 6,553,600 halves
  short* o1_cl = x_cl + 6553600;           // 6,553,600 halves
  float* outp  = (float*)d_out;

  pre_kernel<<<dim3(1664), dim3(256), 0, stream>>>(
      x, bn1g, bn1b, bn1m, bn1v, bn2g, bn2b, bn2m, bn2v,
      w_d1, w_d2, w_om1, w_om2, sc, w1h, w2h, wo1h, wo2h, x_cl);

  dim3 grid(WW / 16, HH / 8, 4);
  dcn_fused<<<grid, dim3(256), 0, stream>>>(
      x_cl, wo1h, b_om1, w1h, sc, sc + 64, nullptr, o1_cl, nullptr);
  dcn_fused<<<grid, dim3(256), 0, stream>>>(
      o1_cl, wo2h, b_om2, w2h, sc + 128, sc + 192, x_cl, nullptr, outp);
}